// Round 15
// baseline (282.977 us; speedup 1.0000x reference)
//
#include <hip/hip_runtime.h>
#include <hip/hip_bf16.h>
#include <math.h>

// ---------------------------------------------------------------------------
// GuoCapSAREncoder round 28:
// (1) conv2 REVERTED to r24/r26 form (67us measured; r27's LDS A-staging was
//     72.9 -- barriers+LDS-occupancy cost > ds_read win. conv2 CLOSED: 7
//     structural variants, floor 67us).
// (2) uhT layout TRANSPOSED to [b][ts][p][o16]. Old [o][p] made k_uhat emit
//     64 scalar 2B stores/thread and k_route read 16 ds_read_u16 per p-iter
//     (2KB stride). Now: uhat stores one bf16x4 per (bi) [16 vector stores],
//     route reads 2x ds_read_b128 per p-iter via XOR-swizzled LDS
//     (addr ^= ((p>>2)&7)<<4, applied at stage-write AND read -> bijective,
//     uniform bank spread). Pure layout change; arithmetic order identical.
// All else frozen from r26 (282.4us best).
// ---------------------------------------------------------------------------

#define EPSF 1e-8f

typedef __bf16 bf16x8 __attribute__((ext_vector_type(8)));
typedef __bf16 bf16x4 __attribute__((ext_vector_type(4)));
typedef float floatx4 __attribute__((ext_vector_type(4)));
typedef float floatx16 __attribute__((ext_vector_type(16)));

// ---- merged weight transposes ---------------------------------------------
__global__ __launch_bounds__(256) void k_t_all(const float* __restrict__ Wr,
                                               const float* __restrict__ wc,
                                               const float* __restrict__ w2,
                                               const float* __restrict__ w1,
                                               __bf16* __restrict__ wrb,
                                               __bf16* __restrict__ wca,
                                               __bf16* __restrict__ w2a,
                                               __bf16* __restrict__ w1b) {
    int i = blockIdx.x * 256 + threadIdx.x;
    if (i < 5242880) {
        wrb[i] = (__bf16)Wr[i];
        return;
    }
    int i2 = i - 5242880;
    if (i2 < 524288) {
        int j = i2 & 7, lane = (i2 >> 3) & 63, f = i2 >> 9;
        int ct = f & 3, ks = (f >> 2) & 1, khw = (f >> 3) & 63, icc = f >> 9;
        int c32 = lane & 31, h = lane >> 5;
        int oc = ct * 32 + c32;
        int ic = icc * 32 + ks * 16 + h * 8 + j;
        wca[i2] = (__bf16)wc[(oc * 64 + ic) * 64 + khw];
        return;
    }
    int i3 = i2 - 524288;
    if (i3 < 204800) {
        int j = i3 & 7, lane = (i3 >> 3) & 63, f = i3 >> 9;
        int mt = f & 1, ks = (f >> 1) & 3, rem = f >> 3;
        int khw = rem % 25, icc = rem / 25;
        int c32 = lane & 31, h = lane >> 5;
        int oc = mt * 32 + c32;
        int ic = icc * 64 + ks * 16 + h * 8 + j;
        w2a[i3] = (__bf16)w2[(oc * 128 + ic) * 25 + khw];
        return;
    }
    int i4 = i3 - 204800;
    if (i4 < 12288) {
        int kt = i4 >> 10, oc = (i4 >> 3) & 127, j = i4 & 7;
        int k = kt * 8 + j;
        w1b[i4] = (__bf16)(k < 81 ? w1[oc * 81 + k] : 0.f);
    }
}

// ---- conv1 9x9 + ReLU + maxpool2, ocg-MERGED -> h1n NHWC bf16 -------------
__global__ __launch_bounds__(256, 3) void k_conv1_mfma(const float* __restrict__ x,
                                                       const __bf16* __restrict__ w1b,
                                                       const float* __restrict__ b1,
                                                       __bf16* __restrict__ h1n) {
    __shared__ float xs[960];                        // 10 rows x 92 fp32 (+pad)
    __shared__ __bf16 Bl[18432];                     // 12kt x 2row x 96pos x 8j
    int py = blockIdx.x, b = blockIdx.y;
    int t = threadIdx.x;
    int lane = t & 63, w = t >> 6;
    int cc = lane & 15, q = lane >> 4;

    const float* xb = x + (size_t)b * 8464 + 2 * py * 92;
    for (int j = t; j < 920; j += 256) xs[j] = xb[j];

    bf16x8 af2[2][3];
#pragma unroll
    for (int g2 = 0; g2 < 2; ++g2)
#pragma unroll
        for (int ks = 0; ks < 3; ++ks)
            af2[g2][ks] = *(const bf16x8*)(w1b + ((ks * 4 + q) * 128 + g2 * 64 + w * 16 + cc) * 8);

    __syncthreads();

    if (t < 192) {
        int row = t / 96, pos = t - (t / 96) * 96;
        int sbase = row * 92 + pos;
        bool pvalid = pos < 84;
#pragma unroll
        for (int kt = 0; kt < 12; ++kt) {
            bf16x8 pk;
#pragma unroll
            for (int j = 0; j < 8; ++j) {
                int k = kt * 8 + j;
                int kh = k / 9, kw = k - kh * 9;
                float v = (pvalid && k < 81) ? xs[sbase + kh * 92 + kw] : 0.f;
                pk[j] = (__bf16)v;
            }
            *(bf16x8*)(Bl + ((kt * 2 + row) * 96 + pos) * 8) = pk;
        }
    }
    __syncthreads();

    floatx4 acc[2][2][6];
#pragma unroll
    for (int g2 = 0; g2 < 2; ++g2)
#pragma unroll
        for (int rr = 0; rr < 2; ++rr)
#pragma unroll
            for (int n6 = 0; n6 < 6; ++n6)
                acc[g2][rr][n6] = (floatx4){0.f, 0.f, 0.f, 0.f};

    const char* Bb = (const char*)Bl + cc * 16 + q * 3072;
#pragma unroll
    for (int rr = 0; rr < 2; ++rr)
#pragma unroll
        for (int n6 = 0; n6 < 6; ++n6) {
#pragma unroll
            for (int ks = 0; ks < 3; ++ks) {
                bf16x8 bf = *(const bf16x8*)(Bb + ks * 12288 + rr * 1536 + n6 * 256);
                acc[0][rr][n6] = __builtin_amdgcn_mfma_f32_16x16x32_bf16(af2[0][ks], bf, acc[0][rr][n6], 0, 0, 0);
                acc[1][rr][n6] = __builtin_amdgcn_mfma_f32_16x16x32_bf16(af2[1][ks], bf, acc[1][rr][n6], 0, 0, 0);
            }
        }

#pragma unroll
    for (int g2 = 0; g2 < 2; ++g2) {
        int oc0 = g2 * 64 + w * 16 + q * 4;
        float4 bv = *(const float4*)(b1 + oc0);
        size_t obase = (((size_t)b * 42 + py) * 42) * 128 + oc0;
#pragma unroll
        for (int n6 = 0; n6 < 6; ++n6) {
            bf16x4 pk;
#pragma unroll
            for (int r = 0; r < 4; ++r) {
                float vert = fmaxf(acc[g2][0][n6][r], acc[g2][1][n6][r]);
                float hz = fmaxf(vert, __shfl_xor(vert, 1, 64));
                float pooled = fmaxf(hz + ((const float*)&bv)[r], 0.f);
                pk[r] = (__bf16)pooled;
            }
            if ((cc & 1) == 0) {
                int px = n6 * 8 + (cc >> 1);
                if (px < 42)
                    *(bf16x4*)(h1n + obase + (size_t)px * 128) = pk;
            }
        }
    }
}

// ---- conv2 5x5 via MFMA 32x32x16, icc-split (r24/r26 form, 67us) ----------
__global__ __launch_bounds__(256) void k_conv2(const __bf16* __restrict__ h1n,
                                               const __bf16* __restrict__ w2a,
                                               float* __restrict__ p01) {
    __shared__ __bf16 ins[25704];                    // 378 pos * 136 B = 51408 B
    int g = blockIdx.x, b = blockIdx.y, icc = blockIdx.z;
    int row0 = g * 5;
    int t = threadIdx.x;
    int lane = t & 63, w = t >> 6;                   // w in [0,4)
    int c32 = lane & 31, h = lane >> 5;
    int validp = (g < 7) ? 190 : 114;
    int ic0 = icc * 64;

    int baseN[2], posi[2];
#pragma unroll
    for (int nt = 0; nt < 2; ++nt) {
        int pi = (w * 2 + nt) * 32 + c32;            // 8 tiles x 32 = 256 slots
        int pc = pi < validp ? pi : validp - 1;
        int r = pc / 38, c = pc - r * 38;
        posi[nt] = pi;
        baseN[nt] = (r * 42 + c) * 136 + h * 16;
    }

    // batched staging: 12 fixed slots per thread (3024 total, tail clamped)
#pragma unroll
    for (int half = 0; half < 2; ++half) {
        uint4 rb[6];
        int lo[6];
#pragma unroll
        for (int k = 0; k < 6; ++k) {
            int j = (half * 6 + k) * 256 + t;
            if (j > 3023) j -= 256;                  // only half=1,k=5,t>=208
            int lr = j / 336, rem = j - lr * 336;
            int ix = rem >> 3, sb = rem & 7;
            int rg = row0 + lr; if (rg > 41) rg = 41;
            rb[k] = *(const uint4*)(h1n + ((((size_t)b * 42 + rg) * 42 + ix) * 128 + ic0 + sb * 8));
            lo[k] = (lr * 42 + ix) * 136 + sb * 16;
        }
#pragma unroll
        for (int k = 0; k < 6; ++k)
            *(uint4*)((char*)ins + lo[k]) = rb[k];
    }

    floatx16 acc[2][2];
#pragma unroll
    for (int mt = 0; mt < 2; ++mt)
#pragma unroll
        for (int nt = 0; nt < 2; ++nt)
#pragma unroll
            for (int i = 0; i < 16; ++i) acc[mt][nt][i] = 0.f;

    const __bf16* wic = w2a + (size_t)icc * 25 * 4096 + (lane << 3);

    // A-frag pipeline: abuf[p][ks*2+mt], rotation over 3 parities
    bf16x8 abuf[3][8];
#pragma unroll
    for (int ks = 0; ks < 4; ++ks) {
        abuf[0][ks * 2]     = *(const bf16x8*)(wic + 0 * 4096 + ks * 1024);
        abuf[0][ks * 2 + 1] = *(const bf16x8*)(wic + 0 * 4096 + ks * 1024 + 512);
        abuf[1][ks * 2]     = *(const bf16x8*)(wic + 1 * 4096 + ks * 1024);
        abuf[1][ks * 2 + 1] = *(const bf16x8*)(wic + 1 * 4096 + ks * 1024 + 512);
    }

    __syncthreads();
#pragma unroll
    for (int khw = 0; khw < 25; ++khw) {
        if (khw + 2 < 25) {
            const __bf16* wk2 = wic + (khw + 2) * 4096;
#pragma unroll
            for (int ks = 0; ks < 4; ++ks) {
                abuf[(khw + 2) % 3][ks * 2]     = *(const bf16x8*)(wk2 + ks * 1024);
                abuf[(khw + 2) % 3][ks * 2 + 1] = *(const bf16x8*)(wk2 + ks * 1024 + 512);
            }
        }
        int kh = khw / 5, kw = khw - kh * 5;
        int doff = (kh * 42 + kw) * 136;
#pragma unroll
        for (int ks = 0; ks < 4; ++ks) {
            bf16x8 a0 = abuf[khw % 3][ks * 2];
            bf16x8 a1 = abuf[khw % 3][ks * 2 + 1];
#pragma unroll
            for (int nt = 0; nt < 2; ++nt) {
                bf16x8 bfr = *(const bf16x8*)((char*)ins + baseN[nt] + doff + ks * 32);
                acc[0][nt] = __builtin_amdgcn_mfma_f32_32x32x16_bf16(a0, bfr, acc[0][nt], 0, 0, 0);
                acc[1][nt] = __builtin_amdgcn_mfma_f32_32x32x16_bf16(a1, bfr, acc[1][nt], 0, 0, 0);
            }
        }
    }
    float* pdst = p01 + (size_t)icc * 5914624;
#pragma unroll
    for (int nt = 0; nt < 2; ++nt) {
        int pi = posi[nt];
        if (pi < validp) {
            int r = pi / 38, c = pi - r * 38;
            int oh = row0 + r;
            size_t obase = (((size_t)b * 38 + oh) * 38 + c) * 64;
#pragma unroll
            for (int mt = 0; mt < 2; ++mt) {
#pragma unroll
                for (int g2 = 0; g2 < 4; ++g2) {
                    int oc0 = mt * 32 + g2 * 8 + h * 4;
                    floatx4 pv;
                    pv[0] = acc[mt][nt][g2 * 4 + 0];
                    pv[1] = acc[mt][nt][g2 * 4 + 1];
                    pv[2] = acc[mt][nt][g2 * 4 + 2];
                    pv[3] = acc[mt][nt][g2 * 4 + 3];
                    *(floatx4*)(pdst + obase + oc0) = pv;
                }
            }
        }
    }
}

// ---- reduce: h2n = bf16(p0 + p1 + b2) -- pure streaming, HBM-rate ---------
__global__ __launch_bounds__(256) void k_reduce_h2(const float* __restrict__ p01,
                                                   const float* __restrict__ b2,
                                                   __bf16* __restrict__ h2n) {
    int i = blockIdx.x * 256 + threadIdx.x;          // 1478656 groups of 4
    if (i >= 1478656) return;
    size_t e = (size_t)i * 4;
    floatx4 a = *(const floatx4*)(p01 + e);
    floatx4 b = *(const floatx4*)(p01 + 5914624 + e);
    floatx4 bv = *(const floatx4*)(b2 + ((i * 4) & 63));
    bf16x4 pk;
    pk.x = (__bf16)(a[0] + b[0] + bv[0]);
    pk.y = (__bf16)(a[1] + b[1] + bv[1]);
    pk.z = (__bf16)(a[2] + b[2] + bv[2]);
    pk.w = (__bf16)(a[3] + b[3] + bv[3]);
    *(bf16x4*)(h2n + e) = pk;
}

// ---- caps conv 8x8 s2 via MFMA 32x32x16, icc-split -> fp32 partials -------
__global__ __launch_bounds__(256, 4) void k_convcaps(const __bf16* __restrict__ h2n,
                                                     const __bf16* __restrict__ wca,
                                                     float* __restrict__ pc) {
    __shared__ __bf16 ins[13680];                    // 380 * 72 B = 27360 B
    int g = blockIdx.x, b = blockIdx.y, icc = blockIdx.z;
    int t = threadIdx.x;
    int lane = t & 63, ct = t >> 6;                  // wave = capsule type
    int c32 = lane & 31, h = lane >> 5;
    int rloc = c32 >> 4, cx = c32 & 15;
    int ic0 = icc * 32;

    floatx16 acc;
#pragma unroll
    for (int i = 0; i < 16; ++i) acc[i] = 0.f;

    int Bbase = (76 * rloc + cx) * 72 + h * 16;      // lane byte base in slab
    {
        uint4 rb[6];
        int lo[6];
#pragma unroll
        for (int k = 0; k < 6; ++k) {
            int j = k * 256 + t;
            if (j > 1519) j -= 256;                  // only k=5, t>=240
            int r = j / 152, rem = j - r * 152;
            int c = rem >> 2, s = rem & 3;
            rb[k] = *(const uint4*)(h2n + ((((size_t)b * 38 + 4 * g + r) * 38 + c) * 64 + ic0 + s * 8));
            int X = (r * 2 + (c & 1)) * 19 + (c >> 1);
            lo[k] = X * 72 + s * 16;
        }
#pragma unroll
        for (int k = 0; k < 6; ++k)
            *(uint4*)((char*)ins + lo[k]) = rb[k];
    }
    __syncthreads();
    const __bf16* wic = wca + ((size_t)icc * 64 * 8 + ct) * 512 + (lane << 3);
#pragma unroll
    for (int khw = 0; khw < 64; ++khw) {
        int kh = khw >> 3, kw = khw & 7;
        int par = kw & 1, k2 = kw >> 1;
        int doff = ((kh * 2 + par) * 19 + k2) * 72;
        const __bf16* wk = wic + khw * 4096;         // 2 ks x 4 ct x 512
#pragma unroll
        for (int ks = 0; ks < 2; ++ks) {
            bf16x8 af = *(const bf16x8*)(wk + ks * 2048);
            bf16x8 bfr = *(const bf16x8*)((char*)ins + Bbase + doff + ks * 32);
            acc = __builtin_amdgcn_mfma_f32_32x32x16_bf16(af, bfr, acc, 0, 0, 0);
        }
    }
    int pos = (2 * g + rloc) * 16 + cx;              // y*16 + x
    float* dst = pc + (size_t)icc * 2097152 + (((size_t)b * 1024 + ct * 256 + pos) * 32);
#pragma unroll
    for (int g2 = 0; g2 < 4; ++g2) {
        floatx4 pv;
        pv[0] = acc[g2 * 4 + 0];
        pv[1] = acc[g2 * 4 + 1];
        pv[2] = acc[g2 * 4 + 2];
        pv[3] = acc[g2 * 4 + 3];
        *(floatx4*)(dst + g2 * 8 + h * 4) = pv;
    }
}

// ---- squash: ub = squash(pc0 + pc1 + bc) -- 20MB streaming ----------------
__global__ __launch_bounds__(256) void k_squash(const float* __restrict__ pc,
                                                const float* __restrict__ bc,
                                                __bf16* __restrict__ ub) {
    int i = blockIdx.x * 256 + threadIdx.x;          // 65536 capsules
    if (i >= 65536) return;
    int ct = (i >> 8) & 3;
    const float* p0 = pc + (size_t)i * 32;
    const float* p1 = pc + 2097152 + (size_t)i * 32;
    const float* bv = bc + ct * 32;
    float vals[32];
    float n2 = 0.f;
#pragma unroll
    for (int k = 0; k < 8; ++k) {
        floatx4 a = *(const floatx4*)(p0 + k * 4);
        floatx4 b = *(const floatx4*)(p1 + k * 4);
        floatx4 bb = *(const floatx4*)(bv + k * 4);
#pragma unroll
        for (int e = 0; e < 4; ++e) {
            float v = a[e] + b[e] + bb[e];
            vals[k * 4 + e] = v;
            n2 = fmaf(v, v, n2);
        }
    }
    float scale = (n2 / (1.f + n2)) / sqrtf(n2 + EPSF);
    __bf16* dst = ub + (size_t)i * 32;
#pragma unroll
    for (int k = 0; k < 8; ++k) {
        bf16x4 pk;
        pk.x = (__bf16)(vals[k * 4 + 0] * scale);
        pk.y = (__bf16)(vals[k * 4 + 1] * scale);
        pk.z = (__bf16)(vals[k * 4 + 2] * scale);
        pk.w = (__bf16)(vals[k * 4 + 3] * scale);
        *(bf16x4*)(dst + k * 4) = pk;
    }
}

// ---- u_hat: ub [64,1024,32] x wrb [1024,10,16,32] -> uhT [b][ts][p][o16] --
__global__ __launch_bounds__(256, 2) void k_uhat(const __bf16* __restrict__ ub,
                                                 const __bf16* __restrict__ wrb,
                                                 __bf16* __restrict__ uhT) {
    int pt = blockIdx.x, ts = blockIdx.y, bz = blockIdx.z;
    int t = threadIdx.x;
    int p = pt * 64 + (t & 63);
    int q = t >> 6;
    bf16x8 wf[4][4];
#pragma unroll
    for (int o4 = 0; o4 < 4; ++o4)
#pragma unroll
        for (int j = 0; j < 4; ++j)
            wf[o4][j] = *(const bf16x8*)(wrb + (((size_t)p * 10 + ts) * 16 + q * 4 + o4) * 32 + j * 8);
#pragma unroll 1
    for (int bi = 0; bi < 16; ++bi) {
        int b = bz * 16 + bi;
        bf16x8 uf[4];
        const bf16x8* up = (const bf16x8*)(ub + ((size_t)b * 1024 + p) * 32);
#pragma unroll
        for (int j = 0; j < 4; ++j) uf[j] = up[j];
        float sv[4];
#pragma unroll
        for (int o4 = 0; o4 < 4; ++o4) {
            float s = 0.f;
#pragma unroll
            for (int j = 0; j < 4; ++j)
#pragma unroll
                for (int e = 0; e < 8; ++e)
                    s = fmaf((float)uf[j][e], (float)wf[o4][j][e], s);
            sv[o4] = s;
        }
        bf16x4 pk;
        pk.x = (__bf16)sv[0];
        pk.y = (__bf16)sv[1];
        pk.z = (__bf16)sv[2];
        pk.w = (__bf16)sv[3];
        *(bf16x4*)(uhT + ((((size_t)b * 10 + ts) * 1024 + p) * 16 + q * 4)) = pk;
    }
}

// ---- fused routing step with bl ping-pong; uhT [p][o16], XOR-swizzled LDS -
#define UHS_ADDR(P, HF) ((((P) << 5) + ((HF) << 4)) ^ ((((P) >> 2) & 7) << 4))
__global__ __launch_bounds__(256) void k_route(const __bf16* __restrict__ uhT,
                                               const float* __restrict__ blR,
                                               float* __restrict__ blW,
                                               float* __restrict__ out,
                                               int first, int dob, int last) {
    __shared__ __bf16 uh_s[16384];                   // 32 KB, swizzled [p][o]
    __shared__ float sred[4][16];
    __shared__ float vs[16];
    int b = blockIdx.x, tt = blockIdx.y;
    int t = threadIdx.x;
    const __bf16* uhb = uhT + ((size_t)b * 10 + tt) * 16384;
#pragma unroll
    for (int k = 0; k < 8; ++k) {
        int j = k * 256 + t;                         // 16B chunk: p=j>>1, hf=j&1
        *(uint4*)((char*)uh_s + UHS_ADDR(j >> 1, j & 1)) =
            *(const uint4*)((const char*)uhb + j * 16);
    }
    __syncthreads();

    // ---- s-phase
    float acc[16];
#pragma unroll
    for (int o = 0; o < 16; ++o) acc[o] = 0.f;
    const float* blb = blR + b * 10240;
    for (int p = t; p < 1024; p += 256) {
        float c;
        if (first) {
            c = 0.1f;
        } else {
            float den = 0.f, et = 0.f;
#pragma unroll
            for (int tp = 0; tp < 10; ++tp) {
                float e = expf(blb[tp * 1024 + p]);
                den += e;
                if (tp == tt) et = e;
            }
            c = et / den;
        }
        bf16x8 u0 = *(const bf16x8*)((char*)uh_s + UHS_ADDR(p, 0));
        bf16x8 u1 = *(const bf16x8*)((char*)uh_s + UHS_ADDR(p, 1));
#pragma unroll
        for (int o = 0; o < 8; ++o) {
            acc[o]     = fmaf(c, (float)u0[o], acc[o]);
            acc[8 + o] = fmaf(c, (float)u1[o], acc[8 + o]);
        }
    }
    int lane = t & 63, wid = t >> 6;
#pragma unroll
    for (int o = 0; o < 16; ++o) {
        float v = acc[o];
#pragma unroll
        for (int off = 32; off >= 1; off >>= 1) v += __shfl_xor(v, off, 64);
        if (lane == 0) sred[wid][o] = v;
    }
    __syncthreads();
    if (t < 16) {
        float s = (sred[0][t] + sred[1][t]) + (sred[2][t] + sred[3][t]);
        float n2 = s * s;
#pragma unroll
        for (int off = 1; off < 16; off <<= 1) n2 += __shfl_xor(n2, off, 16);
        float scale = (n2 / (1.f + n2)) / sqrtf(n2 + EPSF);
        vs[t] = s * scale;
        if (last && t == 0) {
            float sv2 = n2 * scale * scale;
            out[b * 10 + tt] = sqrtf(sv2 + EPSF);
        }
    }
    __syncthreads();

    // ---- b-phase: read own slice of blR, write own slice of blW
    if (dob) {
        const float* blr = blR + (b * 10 + tt) * 1024;
        float* blw = blW + (b * 10 + tt) * 1024;
        for (int p = t; p < 1024; p += 256) {
            bf16x8 u0 = *(const bf16x8*)((char*)uh_s + UHS_ADDR(p, 0));
            bf16x8 u1 = *(const bf16x8*)((char*)uh_s + UHS_ADDR(p, 1));
            float d = 0.f;
#pragma unroll
            for (int o = 0; o < 8; ++o) {
                d = fmaf((float)u0[o], vs[o], d);
                d = fmaf((float)u1[o], vs[8 + o], d);
            }
            blw[p] = first ? d : (blr[p] + d);
        }
    }
}

// ---------------------------------------------------------------------------
extern "C" void kernel_launch(void* const* d_in, const int* in_sizes, int n_in,
                              void* d_out, int out_size, void* d_ws, size_t ws_size,
                              hipStream_t stream) {
    const float* x  = (const float*)d_in[0];
    const float* w1 = (const float*)d_in[1];
    const float* b1 = (const float*)d_in[2];
    const float* w2 = (const float*)d_in[3];
    const float* b2 = (const float*)d_in[4];
    const float* wc = (const float*)d_in[5];
    const float* bc = (const float*)d_in[6];
    const float* Wr = (const float*)d_in[7];
    float* out = (float*)d_out;
    float* ws  = (float*)d_ws;

    // workspace layout (float offsets)
    __bf16* w2a = (__bf16*)(ws);                  // 204800 bf16
    __bf16* wca = (__bf16*)(ws + 102400);         // 524288 bf16
    __bf16* w1b = (__bf16*)(ws + 364544);         // 12288 bf16
    __bf16* h1n = (__bf16*)(ws + 375040);         // 14450688 bf16
    __bf16* h2n = (__bf16*)(ws + 7600384);        // 5914624 bf16
    __bf16* ub  = (__bf16*)(ws + 12654848);       // 2097152 bf16
    float*  blA = ws + 14752000;                  // 655360 f
    __bf16* wrb = (__bf16*)(ws + 15417600);       // 5242880 bf16
    float*  p01 = ws + 18039040;                  // 2 x 5914624 f32 partials
    float*  pc  = ws + 18039040;                  // overlays p01 (dead after reduce)
    float*  blB = ws + 29868288;                  // 655360 f (ping-pong)
    __bf16* uhT = (__bf16*)(ws + 375040);         // overlays h1n (dead by k_uhat)

    k_t_all<<<23376, 256, 0, stream>>>(Wr, wc, w2, w1, wrb, wca, w2a, w1b);
    k_conv1_mfma<<<dim3(42, 64), 256, 0, stream>>>(x, w1b, b1, h1n);
    k_conv2<<<dim3(8, 64, 2), 256, 0, stream>>>(h1n, w2a, p01);
    k_reduce_h2<<<5776, 256, 0, stream>>>(p01, b2, h2n);
    k_convcaps<<<dim3(8, 64, 2), 256, 0, stream>>>(h2n, wca, pc);
    k_squash<<<256, 256, 0, stream>>>(pc, bc, ub);
    k_uhat<<<dim3(16, 10, 4), 256, 0, stream>>>(ub, wrb, uhT);
    k_route<<<dim3(64, 10), 256, 0, stream>>>(uhT, blA, blA, out, 1, 1, 0);
    k_route<<<dim3(64, 10), 256, 0, stream>>>(uhT, blA, blB, out, 0, 1, 0);
    k_route<<<dim3(64, 10), 256, 0, stream>>>(uhT, blB, blB, out, 0, 0, 1);
}

// Round 16
// 273.395 us; speedup vs baseline: 1.0350x; 1.0350x over previous
//
#include <hip/hip_runtime.h>
#include <hip/hip_bf16.h>
#include <math.h>

// ---------------------------------------------------------------------------
// GuoCapSAREncoder round 29: k_uhat -> MFMA. The einsum is 1024 independent
// [160,32]x[32,64] GEMMs (K=32 == one mfma_f32_16x16x32_bf16). Old scalar
// version: 2048 MACs/thread with 2 bf16->f32 converts each (~3 VALU/MAC).
// New: wrb stored FRAG-READY ([p][ts][lane][8], gather in k_t_all), B-frag
// 16B/lane from L2-resident ub, one MFMA + one bf16x4 store per (p,ts,bt).
// C lane mapping (col=b, row=o-quad) writes r28's [b][ts][p][o16] uhT layout
// directly (r28 was the prerequisite). MFMA tree-order vs serial fmaf changes
// rounding below bf16 precision; tolerance has 3x headroom.
// All else byte-identical to r28 (conv2 66.5us r24-form, routes swizzled).
// ---------------------------------------------------------------------------

#define EPSF 1e-8f

typedef __bf16 bf16x8 __attribute__((ext_vector_type(8)));
typedef __bf16 bf16x4 __attribute__((ext_vector_type(4)));
typedef float floatx4 __attribute__((ext_vector_type(4)));
typedef float floatx16 __attribute__((ext_vector_type(16)));

// ---- merged weight transposes ---------------------------------------------
// wrb now FRAG-READY: [p*10+ts][lane][8]: elem = Wr[p][ts][o=lane&15][k=(lane>>4)*8+e]
__global__ __launch_bounds__(256) void k_t_all(const float* __restrict__ Wr,
                                               const float* __restrict__ wc,
                                               const float* __restrict__ w2,
                                               const float* __restrict__ w1,
                                               __bf16* __restrict__ wrb,
                                               __bf16* __restrict__ wca,
                                               __bf16* __restrict__ w2a,
                                               __bf16* __restrict__ w1b) {
    int i = blockIdx.x * 256 + threadIdx.x;
    if (i < 5242880) {
        int e = i & 7, l = (i >> 3) & 63;
        int pt_ = i >> 9;                            // p*10 + ts
        int o = l & 15, k = (l >> 4) * 8 + e;
        wrb[i] = (__bf16)Wr[((size_t)pt_ * 16 + o) * 32 + k];
        return;
    }
    int i2 = i - 5242880;
    if (i2 < 524288) {
        int j = i2 & 7, lane = (i2 >> 3) & 63, f = i2 >> 9;
        int ct = f & 3, ks = (f >> 2) & 1, khw = (f >> 3) & 63, icc = f >> 9;
        int c32 = lane & 31, h = lane >> 5;
        int oc = ct * 32 + c32;
        int ic = icc * 32 + ks * 16 + h * 8 + j;
        wca[i2] = (__bf16)wc[(oc * 64 + ic) * 64 + khw];
        return;
    }
    int i3 = i2 - 524288;
    if (i3 < 204800) {
        int j = i3 & 7, lane = (i3 >> 3) & 63, f = i3 >> 9;
        int mt = f & 1, ks = (f >> 1) & 3, rem = f >> 3;
        int khw = rem % 25, icc = rem / 25;
        int c32 = lane & 31, h = lane >> 5;
        int oc = mt * 32 + c32;
        int ic = icc * 64 + ks * 16 + h * 8 + j;
        w2a[i3] = (__bf16)w2[(oc * 128 + ic) * 25 + khw];
        return;
    }
    int i4 = i3 - 204800;
    if (i4 < 12288) {
        int kt = i4 >> 10, oc = (i4 >> 3) & 127, j = i4 & 7;
        int k = kt * 8 + j;
        w1b[i4] = (__bf16)(k < 81 ? w1[oc * 81 + k] : 0.f);
    }
}

// ---- conv1 9x9 + ReLU + maxpool2, ocg-MERGED -> h1n NHWC bf16 -------------
__global__ __launch_bounds__(256, 3) void k_conv1_mfma(const float* __restrict__ x,
                                                       const __bf16* __restrict__ w1b,
                                                       const float* __restrict__ b1,
                                                       __bf16* __restrict__ h1n) {
    __shared__ float xs[960];                        // 10 rows x 92 fp32 (+pad)
    __shared__ __bf16 Bl[18432];                     // 12kt x 2row x 96pos x 8j
    int py = blockIdx.x, b = blockIdx.y;
    int t = threadIdx.x;
    int lane = t & 63, w = t >> 6;
    int cc = lane & 15, q = lane >> 4;

    const float* xb = x + (size_t)b * 8464 + 2 * py * 92;
    for (int j = t; j < 920; j += 256) xs[j] = xb[j];

    bf16x8 af2[2][3];
#pragma unroll
    for (int g2 = 0; g2 < 2; ++g2)
#pragma unroll
        for (int ks = 0; ks < 3; ++ks)
            af2[g2][ks] = *(const bf16x8*)(w1b + ((ks * 4 + q) * 128 + g2 * 64 + w * 16 + cc) * 8);

    __syncthreads();

    if (t < 192) {
        int row = t / 96, pos = t - (t / 96) * 96;
        int sbase = row * 92 + pos;
        bool pvalid = pos < 84;
#pragma unroll
        for (int kt = 0; kt < 12; ++kt) {
            bf16x8 pk;
#pragma unroll
            for (int j = 0; j < 8; ++j) {
                int k = kt * 8 + j;
                int kh = k / 9, kw = k - kh * 9;
                float v = (pvalid && k < 81) ? xs[sbase + kh * 92 + kw] : 0.f;
                pk[j] = (__bf16)v;
            }
            *(bf16x8*)(Bl + ((kt * 2 + row) * 96 + pos) * 8) = pk;
        }
    }
    __syncthreads();

    floatx4 acc[2][2][6];
#pragma unroll
    for (int g2 = 0; g2 < 2; ++g2)
#pragma unroll
        for (int rr = 0; rr < 2; ++rr)
#pragma unroll
            for (int n6 = 0; n6 < 6; ++n6)
                acc[g2][rr][n6] = (floatx4){0.f, 0.f, 0.f, 0.f};

    const char* Bb = (const char*)Bl + cc * 16 + q * 3072;
#pragma unroll
    for (int rr = 0; rr < 2; ++rr)
#pragma unroll
        for (int n6 = 0; n6 < 6; ++n6) {
#pragma unroll
            for (int ks = 0; ks < 3; ++ks) {
                bf16x8 bf = *(const bf16x8*)(Bb + ks * 12288 + rr * 1536 + n6 * 256);
                acc[0][rr][n6] = __builtin_amdgcn_mfma_f32_16x16x32_bf16(af2[0][ks], bf, acc[0][rr][n6], 0, 0, 0);
                acc[1][rr][n6] = __builtin_amdgcn_mfma_f32_16x16x32_bf16(af2[1][ks], bf, acc[1][rr][n6], 0, 0, 0);
            }
        }

#pragma unroll
    for (int g2 = 0; g2 < 2; ++g2) {
        int oc0 = g2 * 64 + w * 16 + q * 4;
        float4 bv = *(const float4*)(b1 + oc0);
        size_t obase = (((size_t)b * 42 + py) * 42) * 128 + oc0;
#pragma unroll
        for (int n6 = 0; n6 < 6; ++n6) {
            bf16x4 pk;
#pragma unroll
            for (int r = 0; r < 4; ++r) {
                float vert = fmaxf(acc[g2][0][n6][r], acc[g2][1][n6][r]);
                float hz = fmaxf(vert, __shfl_xor(vert, 1, 64));
                float pooled = fmaxf(hz + ((const float*)&bv)[r], 0.f);
                pk[r] = (__bf16)pooled;
            }
            if ((cc & 1) == 0) {
                int px = n6 * 8 + (cc >> 1);
                if (px < 42)
                    *(bf16x4*)(h1n + obase + (size_t)px * 128) = pk;
            }
        }
    }
}

// ---- conv2 5x5 via MFMA 32x32x16, icc-split (r24/r26 form, 67us) ----------
__global__ __launch_bounds__(256) void k_conv2(const __bf16* __restrict__ h1n,
                                               const __bf16* __restrict__ w2a,
                                               float* __restrict__ p01) {
    __shared__ __bf16 ins[25704];                    // 378 pos * 136 B = 51408 B
    int g = blockIdx.x, b = blockIdx.y, icc = blockIdx.z;
    int row0 = g * 5;
    int t = threadIdx.x;
    int lane = t & 63, w = t >> 6;                   // w in [0,4)
    int c32 = lane & 31, h = lane >> 5;
    int validp = (g < 7) ? 190 : 114;
    int ic0 = icc * 64;

    int baseN[2], posi[2];
#pragma unroll
    for (int nt = 0; nt < 2; ++nt) {
        int pi = (w * 2 + nt) * 32 + c32;            // 8 tiles x 32 = 256 slots
        int pc = pi < validp ? pi : validp - 1;
        int r = pc / 38, c = pc - r * 38;
        posi[nt] = pi;
        baseN[nt] = (r * 42 + c) * 136 + h * 16;
    }

    // batched staging: 12 fixed slots per thread (3024 total, tail clamped)
#pragma unroll
    for (int half = 0; half < 2; ++half) {
        uint4 rb[6];
        int lo[6];
#pragma unroll
        for (int k = 0; k < 6; ++k) {
            int j = (half * 6 + k) * 256 + t;
            if (j > 3023) j -= 256;                  // only half=1,k=5,t>=208
            int lr = j / 336, rem = j - lr * 336;
            int ix = rem >> 3, sb = rem & 7;
            int rg = row0 + lr; if (rg > 41) rg = 41;
            rb[k] = *(const uint4*)(h1n + ((((size_t)b * 42 + rg) * 42 + ix) * 128 + ic0 + sb * 8));
            lo[k] = (lr * 42 + ix) * 136 + sb * 16;
        }
#pragma unroll
        for (int k = 0; k < 6; ++k)
            *(uint4*)((char*)ins + lo[k]) = rb[k];
    }

    floatx16 acc[2][2];
#pragma unroll
    for (int mt = 0; mt < 2; ++mt)
#pragma unroll
        for (int nt = 0; nt < 2; ++nt)
#pragma unroll
            for (int i = 0; i < 16; ++i) acc[mt][nt][i] = 0.f;

    const __bf16* wic = w2a + (size_t)icc * 25 * 4096 + (lane << 3);

    // A-frag pipeline: abuf[p][ks*2+mt], rotation over 3 parities
    bf16x8 abuf[3][8];
#pragma unroll
    for (int ks = 0; ks < 4; ++ks) {
        abuf[0][ks * 2]     = *(const bf16x8*)(wic + 0 * 4096 + ks * 1024);
        abuf[0][ks * 2 + 1] = *(const bf16x8*)(wic + 0 * 4096 + ks * 1024 + 512);
        abuf[1][ks * 2]     = *(const bf16x8*)(wic + 1 * 4096 + ks * 1024);
        abuf[1][ks * 2 + 1] = *(const bf16x8*)(wic + 1 * 4096 + ks * 1024 + 512);
    }

    __syncthreads();
#pragma unroll
    for (int khw = 0; khw < 25; ++khw) {
        if (khw + 2 < 25) {
            const __bf16* wk2 = wic + (khw + 2) * 4096;
#pragma unroll
            for (int ks = 0; ks < 4; ++ks) {
                abuf[(khw + 2) % 3][ks * 2]     = *(const bf16x8*)(wk2 + ks * 1024);
                abuf[(khw + 2) % 3][ks * 2 + 1] = *(const bf16x8*)(wk2 + ks * 1024 + 512);
            }
        }
        int kh = khw / 5, kw = khw - kh * 5;
        int doff = (kh * 42 + kw) * 136;
#pragma unroll
        for (int ks = 0; ks < 4; ++ks) {
            bf16x8 a0 = abuf[khw % 3][ks * 2];
            bf16x8 a1 = abuf[khw % 3][ks * 2 + 1];
#pragma unroll
            for (int nt = 0; nt < 2; ++nt) {
                bf16x8 bfr = *(const bf16x8*)((char*)ins + baseN[nt] + doff + ks * 32);
                acc[0][nt] = __builtin_amdgcn_mfma_f32_32x32x16_bf16(a0, bfr, acc[0][nt], 0, 0, 0);
                acc[1][nt] = __builtin_amdgcn_mfma_f32_32x32x16_bf16(a1, bfr, acc[1][nt], 0, 0, 0);
            }
        }
    }
    float* pdst = p01 + (size_t)icc * 5914624;
#pragma unroll
    for (int nt = 0; nt < 2; ++nt) {
        int pi = posi[nt];
        if (pi < validp) {
            int r = pi / 38, c = pi - r * 38;
            int oh = row0 + r;
            size_t obase = (((size_t)b * 38 + oh) * 38 + c) * 64;
#pragma unroll
            for (int mt = 0; mt < 2; ++mt) {
#pragma unroll
                for (int g2 = 0; g2 < 4; ++g2) {
                    int oc0 = mt * 32 + g2 * 8 + h * 4;
                    floatx4 pv;
                    pv[0] = acc[mt][nt][g2 * 4 + 0];
                    pv[1] = acc[mt][nt][g2 * 4 + 1];
                    pv[2] = acc[mt][nt][g2 * 4 + 2];
                    pv[3] = acc[mt][nt][g2 * 4 + 3];
                    *(floatx4*)(pdst + obase + oc0) = pv;
                }
            }
        }
    }
}

// ---- reduce: h2n = bf16(p0 + p1 + b2) -- pure streaming, HBM-rate ---------
__global__ __launch_bounds__(256) void k_reduce_h2(const float* __restrict__ p01,
                                                   const float* __restrict__ b2,
                                                   __bf16* __restrict__ h2n) {
    int i = blockIdx.x * 256 + threadIdx.x;          // 1478656 groups of 4
    if (i >= 1478656) return;
    size_t e = (size_t)i * 4;
    floatx4 a = *(const floatx4*)(p01 + e);
    floatx4 b = *(const floatx4*)(p01 + 5914624 + e);
    floatx4 bv = *(const floatx4*)(b2 + ((i * 4) & 63));
    bf16x4 pk;
    pk.x = (__bf16)(a[0] + b[0] + bv[0]);
    pk.y = (__bf16)(a[1] + b[1] + bv[1]);
    pk.z = (__bf16)(a[2] + b[2] + bv[2]);
    pk.w = (__bf16)(a[3] + b[3] + bv[3]);
    *(bf16x4*)(h2n + e) = pk;
}

// ---- caps conv 8x8 s2 via MFMA 32x32x16, icc-split -> fp32 partials -------
__global__ __launch_bounds__(256, 4) void k_convcaps(const __bf16* __restrict__ h2n,
                                                     const __bf16* __restrict__ wca,
                                                     float* __restrict__ pc) {
    __shared__ __bf16 ins[13680];                    // 380 * 72 B = 27360 B
    int g = blockIdx.x, b = blockIdx.y, icc = blockIdx.z;
    int t = threadIdx.x;
    int lane = t & 63, ct = t >> 6;                  // wave = capsule type
    int c32 = lane & 31, h = lane >> 5;
    int rloc = c32 >> 4, cx = c32 & 15;
    int ic0 = icc * 32;

    floatx16 acc;
#pragma unroll
    for (int i = 0; i < 16; ++i) acc[i] = 0.f;

    int Bbase = (76 * rloc + cx) * 72 + h * 16;      // lane byte base in slab
    {
        uint4 rb[6];
        int lo[6];
#pragma unroll
        for (int k = 0; k < 6; ++k) {
            int j = k * 256 + t;
            if (j > 1519) j -= 256;                  // only k=5, t>=240
            int r = j / 152, rem = j - r * 152;
            int c = rem >> 2, s = rem & 3;
            rb[k] = *(const uint4*)(h2n + ((((size_t)b * 38 + 4 * g + r) * 38 + c) * 64 + ic0 + s * 8));
            int X = (r * 2 + (c & 1)) * 19 + (c >> 1);
            lo[k] = X * 72 + s * 16;
        }
#pragma unroll
        for (int k = 0; k < 6; ++k)
            *(uint4*)((char*)ins + lo[k]) = rb[k];
    }
    __syncthreads();
    const __bf16* wic = wca + ((size_t)icc * 64 * 8 + ct) * 512 + (lane << 3);
#pragma unroll
    for (int khw = 0; khw < 64; ++khw) {
        int kh = khw >> 3, kw = khw & 7;
        int par = kw & 1, k2 = kw >> 1;
        int doff = ((kh * 2 + par) * 19 + k2) * 72;
        const __bf16* wk = wic + khw * 4096;         // 2 ks x 4 ct x 512
#pragma unroll
        for (int ks = 0; ks < 2; ++ks) {
            bf16x8 af = *(const bf16x8*)(wk + ks * 2048);
            bf16x8 bfr = *(const bf16x8*)((char*)ins + Bbase + doff + ks * 32);
            acc = __builtin_amdgcn_mfma_f32_32x32x16_bf16(af, bfr, acc, 0, 0, 0);
        }
    }
    int pos = (2 * g + rloc) * 16 + cx;              // y*16 + x
    float* dst = pc + (size_t)icc * 2097152 + (((size_t)b * 1024 + ct * 256 + pos) * 32);
#pragma unroll
    for (int g2 = 0; g2 < 4; ++g2) {
        floatx4 pv;
        pv[0] = acc[g2 * 4 + 0];
        pv[1] = acc[g2 * 4 + 1];
        pv[2] = acc[g2 * 4 + 2];
        pv[3] = acc[g2 * 4 + 3];
        *(floatx4*)(dst + g2 * 8 + h * 4) = pv;
    }
}

// ---- squash: ub = squash(pc0 + pc1 + bc) -- 20MB streaming ----------------
__global__ __launch_bounds__(256) void k_squash(const float* __restrict__ pc,
                                                const float* __restrict__ bc,
                                                __bf16* __restrict__ ub) {
    int i = blockIdx.x * 256 + threadIdx.x;          // 65536 capsules
    if (i >= 65536) return;
    int ct = (i >> 8) & 3;
    const float* p0 = pc + (size_t)i * 32;
    const float* p1 = pc + 2097152 + (size_t)i * 32;
    const float* bv = bc + ct * 32;
    float vals[32];
    float n2 = 0.f;
#pragma unroll
    for (int k = 0; k < 8; ++k) {
        floatx4 a = *(const floatx4*)(p0 + k * 4);
        floatx4 b = *(const floatx4*)(p1 + k * 4);
        floatx4 bb = *(const floatx4*)(bv + k * 4);
#pragma unroll
        for (int e = 0; e < 4; ++e) {
            float v = a[e] + b[e] + bb[e];
            vals[k * 4 + e] = v;
            n2 = fmaf(v, v, n2);
        }
    }
    float scale = (n2 / (1.f + n2)) / sqrtf(n2 + EPSF);
    __bf16* dst = ub + (size_t)i * 32;
#pragma unroll
    for (int k = 0; k < 8; ++k) {
        bf16x4 pk;
        pk.x = (__bf16)(vals[k * 4 + 0] * scale);
        pk.y = (__bf16)(vals[k * 4 + 1] * scale);
        pk.z = (__bf16)(vals[k * 4 + 2] * scale);
        pk.w = (__bf16)(vals[k * 4 + 3] * scale);
        *(bf16x4*)(dst + k * 4) = pk;
    }
}

// ---- u_hat via MFMA: per p, W_p[16o,32] x u[16b,32]^T -> uhT [b][ts][p][o16]
// grid (64, 10); wave bt = t>>6 handles batch tile bt*16..+15 over 16 p.
__global__ __launch_bounds__(256) void k_uhat(const __bf16* __restrict__ ub,
                                              const __bf16* __restrict__ wrf,
                                              __bf16* __restrict__ uhT) {
    int pg = blockIdx.x, ts = blockIdx.y;
    int t = threadIdx.x;
    int lane = t & 63, bt = t >> 6;
    int bcol = bt * 16 + (lane & 15);
    int ko = lane >> 4;
    const __bf16* ubase = ub + (size_t)bcol * 32768 + ko * 8;    // [b][p][32]
    __bf16* obase = uhT + ((size_t)bcol * 10 + ts) * 16384 + ko * 4;
#pragma unroll 4
    for (int i = 0; i < 16; ++i) {
        int p = pg * 16 + i;
        bf16x8 a = *(const bf16x8*)(wrf + (((size_t)p * 10 + ts) * 64 + lane) * 8);
        bf16x8 bb = *(const bf16x8*)(ubase + (size_t)p * 32);
        floatx4 c = (floatx4){0.f, 0.f, 0.f, 0.f};
        c = __builtin_amdgcn_mfma_f32_16x16x32_bf16(a, bb, c, 0, 0, 0);
        bf16x4 pk;
        pk.x = (__bf16)c[0];
        pk.y = (__bf16)c[1];
        pk.z = (__bf16)c[2];
        pk.w = (__bf16)c[3];
        *(bf16x4*)(obase + (size_t)p * 16) = pk;
    }
}

// ---- fused routing step with bl ping-pong; uhT [p][o16], XOR-swizzled LDS -
#define UHS_ADDR(P, HF) ((((P) << 5) + ((HF) << 4)) ^ ((((P) >> 2) & 7) << 4))
__global__ __launch_bounds__(256) void k_route(const __bf16* __restrict__ uhT,
                                               const float* __restrict__ blR,
                                               float* __restrict__ blW,
                                               float* __restrict__ out,
                                               int first, int dob, int last) {
    __shared__ __bf16 uh_s[16384];                   // 32 KB, swizzled [p][o]
    __shared__ float sred[4][16];
    __shared__ float vs[16];
    int b = blockIdx.x, tt = blockIdx.y;
    int t = threadIdx.x;
    const __bf16* uhb = uhT + ((size_t)b * 10 + tt) * 16384;
#pragma unroll
    for (int k = 0; k < 8; ++k) {
        int j = k * 256 + t;                         // 16B chunk: p=j>>1, hf=j&1
        *(uint4*)((char*)uh_s + UHS_ADDR(j >> 1, j & 1)) =
            *(const uint4*)((const char*)uhb + j * 16);
    }
    __syncthreads();

    // ---- s-phase
    float acc[16];
#pragma unroll
    for (int o = 0; o < 16; ++o) acc[o] = 0.f;
    const float* blb = blR + b * 10240;
    for (int p = t; p < 1024; p += 256) {
        float c;
        if (first) {
            c = 0.1f;
        } else {
            float den = 0.f, et = 0.f;
#pragma unroll
            for (int tp = 0; tp < 10; ++tp) {
                float e = expf(blb[tp * 1024 + p]);
                den += e;
                if (tp == tt) et = e;
            }
            c = et / den;
        }
        bf16x8 u0 = *(const bf16x8*)((char*)uh_s + UHS_ADDR(p, 0));
        bf16x8 u1 = *(const bf16x8*)((char*)uh_s + UHS_ADDR(p, 1));
#pragma unroll
        for (int o = 0; o < 8; ++o) {
            acc[o]     = fmaf(c, (float)u0[o], acc[o]);
            acc[8 + o] = fmaf(c, (float)u1[o], acc[8 + o]);
        }
    }
    int lane = t & 63, wid = t >> 6;
#pragma unroll
    for (int o = 0; o < 16; ++o) {
        float v = acc[o];
#pragma unroll
        for (int off = 32; off >= 1; off >>= 1) v += __shfl_xor(v, off, 64);
        if (lane == 0) sred[wid][o] = v;
    }
    __syncthreads();
    if (t < 16) {
        float s = (sred[0][t] + sred[1][t]) + (sred[2][t] + sred[3][t]);
        float n2 = s * s;
#pragma unroll
        for (int off = 1; off < 16; off <<= 1) n2 += __shfl_xor(n2, off, 16);
        float scale = (n2 / (1.f + n2)) / sqrtf(n2 + EPSF);
        vs[t] = s * scale;
        if (last && t == 0) {
            float sv2 = n2 * scale * scale;
            out[b * 10 + tt] = sqrtf(sv2 + EPSF);
        }
    }
    __syncthreads();

    // ---- b-phase: read own slice of blR, write own slice of blW
    if (dob) {
        const float* blr = blR + (b * 10 + tt) * 1024;
        float* blw = blW + (b * 10 + tt) * 1024;
        for (int p = t; p < 1024; p += 256) {
            bf16x8 u0 = *(const bf16x8*)((char*)uh_s + UHS_ADDR(p, 0));
            bf16x8 u1 = *(const bf16x8*)((char*)uh_s + UHS_ADDR(p, 1));
            float d = 0.f;
#pragma unroll
            for (int o = 0; o < 8; ++o) {
                d = fmaf((float)u0[o], vs[o], d);
                d = fmaf((float)u1[o], vs[8 + o], d);
            }
            blw[p] = first ? d : (blr[p] + d);
        }
    }
}

// ---------------------------------------------------------------------------
extern "C" void kernel_launch(void* const* d_in, const int* in_sizes, int n_in,
                              void* d_out, int out_size, void* d_ws, size_t ws_size,
                              hipStream_t stream) {
    const float* x  = (const float*)d_in[0];
    const float* w1 = (const float*)d_in[1];
    const float* b1 = (const float*)d_in[2];
    const float* w2 = (const float*)d_in[3];
    const float* b2 = (const float*)d_in[4];
    const float* wc = (const float*)d_in[5];
    const float* bc = (const float*)d_in[6];
    const float* Wr = (const float*)d_in[7];
    float* out = (float*)d_out;
    float* ws  = (float*)d_ws;

    // workspace layout (float offsets)
    __bf16* w2a = (__bf16*)(ws);                  // 204800 bf16
    __bf16* wca = (__bf16*)(ws + 102400);         // 524288 bf16
    __bf16* w1b = (__bf16*)(ws + 364544);         // 12288 bf16
    __bf16* h1n = (__bf16*)(ws + 375040);         // 14450688 bf16
    __bf16* h2n = (__bf16*)(ws + 7600384);        // 5914624 bf16
    __bf16* ub  = (__bf16*)(ws + 12654848);       // 2097152 bf16
    float*  blA = ws + 14752000;                  // 655360 f
    __bf16* wrb = (__bf16*)(ws + 15417600);       // 5242880 bf16 (frag-ready)
    float*  p01 = ws + 18039040;                  // 2 x 5914624 f32 partials
    float*  pc  = ws + 18039040;                  // overlays p01 (dead after reduce)
    float*  blB = ws + 29868288;                  // 655360 f (ping-pong)
    __bf16* uhT = (__bf16*)(ws + 375040);         // overlays h1n (dead by k_uhat)

    k_t_all<<<23376, 256, 0, stream>>>(Wr, wc, w2, w1, wrb, wca, w2a, w1b);
    k_conv1_mfma<<<dim3(42, 64), 256, 0, stream>>>(x, w1b, b1, h1n);
    k_conv2<<<dim3(8, 64, 2), 256, 0, stream>>>(h1n, w2a, p01);
    k_reduce_h2<<<5776, 256, 0, stream>>>(p01, b2, h2n);
    k_convcaps<<<dim3(8, 64, 2), 256, 0, stream>>>(h2n, wca, pc);
    k_squash<<<256, 256, 0, stream>>>(pc, bc, ub);
    k_uhat<<<dim3(64, 10), 256, 0, stream>>>(ub, wrb, uhT);
    k_route<<<dim3(64, 10), 256, 0, stream>>>(uhT, blA, blA, out, 1, 1, 0);
    k_route<<<dim3(64, 10), 256, 0, stream>>>(uhT, blA, blB, out, 0, 1, 0);
    k_route<<<dim3(64, 10), 256, 0, stream>>>(uhT, blB, blB, out, 0, 0, 1);
}